// Round 5
// baseline (86.804 us; speedup 1.0000x reference)
//
#include <hip/hip_runtime.h>
#include <stdint.h>

typedef unsigned long long u64;
typedef unsigned short u16;

#define C_SIZE 32768
#define N_SIZE 900
#define B_SIZE 128
#define NWORDS 15      // ceil(900/64)
#define WSTRIDE 16     // ybits row stride in u64
#define NBUCKETS 901   // d in [0, 900]
#define IPB 8          // items per block in compute_rep
#define CHUNKS 16      // row chunks in compute_rep
#define ROWS_PER_CHUNK (C_SIZE / CHUNKS)   // 2048
#define EMPTY 0x7fffffff

// ---------------------------------------------------------------------------
// Kernel A: pack 0/1 float rows into bitmasks, one wave per row.
// cache rows -> TRANSPOSED cbitsT[w][row] (so compute_rep reads coalesce);
// y_true rows -> row-major ybits[item][w].
// ---------------------------------------------------------------------------
__global__ __launch_bounds__(256) void pack_bits_all(const float* __restrict__ cache,
                                                     const float* __restrict__ y_true,
                                                     u64* __restrict__ cbitsT,
                                                     u64* __restrict__ ybits) {
    int wave = (int)((blockIdx.x * blockDim.x + threadIdx.x) >> 6);
    int lane = (int)(threadIdx.x & 63);
    const float* row;
    bool is_cache;
    int r;
    if (wave < C_SIZE) {
        is_cache = true; r = wave;
        row = cache + (size_t)r * N_SIZE;
    } else if (wave < C_SIZE + B_SIZE) {
        is_cache = false; r = wave - C_SIZE;
        row = y_true + (size_t)r * N_SIZE;
    } else {
        return;
    }
    u64 myword = 0;
#pragma unroll
    for (int w = 0; w < NWORDS; ++w) {
        int j = w * 64 + lane;
        float v = 0.0f;
        if (j < N_SIZE) v = row[j];
        u64 m = __ballot(v != 0.0f);
        if (lane == w) myword = m;
    }
    if (lane < NWORDS) {
        if (is_cache) cbitsT[(size_t)lane * C_SIZE + r] = myword;
        else          ybits[(size_t)r * WSTRIDE + lane] = myword;
    }
}

// ---------------------------------------------------------------------------
// Kernel B: per-(chunk, 8-item-group) bucket-argmin into private u16 slice.
// Row bits: coalesced loads from transposed cbitsT. y bits: LDS broadcast.
// LDS atomicMin; flush full table (0 = empty, else row-in-chunk+1) -> no
// global init needed. Cross-chunk min is "first non-empty chunk" since row
// indices are ordered by chunk.
// repc layout: [CHUNKS][B_SIZE][NBUCKETS] u16
// ---------------------------------------------------------------------------
__global__ __launch_bounds__(256) void compute_rep(const u64* __restrict__ cbitsT,
                                                   const u64* __restrict__ ybits,
                                                   u16* __restrict__ repc) {
    __shared__ int lrep[IPB][NBUCKETS];
    __shared__ u64 yl[IPB][NWORDS];
    const int tid = (int)threadIdx.x;
    for (int idx = tid; idx < IPB * NBUCKETS; idx += 256)
        ((int*)lrep)[idx] = EMPTY;
    const int item0 = (int)blockIdx.y * IPB;
    for (int idx = tid; idx < IPB * NWORDS; idx += 256) {
        int it = idx / NWORDS, w = idx % NWORDS;
        yl[it][w] = ybits[(size_t)(item0 + it) * WSTRIDE + w];
    }
    __syncthreads();

    const int kbase = (int)blockIdx.x * ROWS_PER_CHUNK;

#pragma unroll 1
    for (int i = 0; i < ROWS_PER_CHUNK / 256; ++i) {   // 8 iters
        int k = kbase + i * 256 + tid;
        u64 ck[NWORDS];
#pragma unroll
        for (int w = 0; w < NWORDS; ++w) ck[w] = cbitsT[(size_t)w * C_SIZE + k];
#pragma unroll
        for (int it = 0; it < IPB; ++it) {
            int d = 0;
#pragma unroll
            for (int w = 0; w < NWORDS; ++w) d += (int)__popcll(ck[w] & yl[it][w]);
            atomicMin(&lrep[it][d], k);
        }
    }
    __syncthreads();

    for (int t = tid; t < NBUCKETS; t += 256) {
#pragma unroll
        for (int it = 0; it < IPB; ++it) {
            int v = lrep[it][t];
            repc[((size_t)blockIdx.x * B_SIZE + (item0 + it)) * NBUCKETS + t] =
                (v == EMPTY) ? (u16)0 : (u16)(v - kbase + 1);
        }
    }
}

// ---------------------------------------------------------------------------
// Kernel C: fold the 16-way chunk combine (first non-empty chunk = min, via
// min over decoded candidates), write combined rep, and compute masked-sum
// dot s[rep] where present.
// ---------------------------------------------------------------------------
__global__ __launch_bounds__(256) void gather_s(const u64* __restrict__ cbitsT,
                                                const float* __restrict__ y_hat,
                                                const u16* __restrict__ repc,
                                                int* __restrict__ rep,
                                                float* __restrict__ svals) {
    int item = (int)blockIdx.y;
    int wave_in_item = (int)(blockIdx.x * (blockDim.x >> 6) + (threadIdx.x >> 6)); // 0..63
    int lane = (int)(threadIdx.x & 63);
    const float* yh = y_hat + (size_t)item * N_SIZE;

    for (int t = wave_in_item; t < NBUCKETS; t += 64) {
        int k = EMPTY;
#pragma unroll
        for (int c = 0; c < CHUNKS; ++c) {
            int v = (int)repc[((size_t)c * B_SIZE + item) * NBUCKETS + t];
            int cand = v ? (c * ROWS_PER_CHUNK + v - 1) : EMPTY;
            k = min(k, cand);
        }
        if (lane == 0) rep[item * NBUCKETS + t] = k;
        if (k >= C_SIZE) continue;          // empty bucket
        float s = 0.0f;
#pragma unroll
        for (int w = 0; w < NWORDS; ++w) {
            u64 word = cbitsT[(size_t)w * C_SIZE + k]; // broadcast
            int j = w * 64 + lane;
            if (j < N_SIZE && ((word >> lane) & 1ull)) s += yh[j];
        }
#pragma unroll
        for (int off = 32; off; off >>= 1) s += __shfl_xor(s, off, 64);
        if (lane == 0) svals[item * NBUCKETS + t] = s;
    }
}

// ---------------------------------------------------------------------------
// Kernel D1: per-item loss. One block per item, 256 threads strided over
// the 901 buckets; LDS reduce for tmax, then relu-sum + count.
// ---------------------------------------------------------------------------
__global__ __launch_bounds__(256) void finalize_item(const int* __restrict__ rep,
                                                     const float* __restrict__ svals,
                                                     float* __restrict__ loss) {
    int item = (int)blockIdx.x;
    const int* r = rep + item * NBUCKETS;
    const float* s = svals + item * NBUCKETS;
    int tid = (int)threadIdx.x;

    __shared__ int   red_i[256];
    __shared__ float red_f[256];
    __shared__ int   red_c[256];

    int tmax = -1;
    for (int t = tid; t < NBUCKETS; t += 256)
        if (r[t] < C_SIZE) tmax = t;
    red_i[tid] = tmax;
    __syncthreads();
    for (int off = 128; off; off >>= 1) {
        if (tid < off) red_i[tid] = max(red_i[tid], red_i[tid + off]);
        __syncthreads();
    }
    int tm = red_i[0];
    float best = (tm >= 0) ? s[tm] : 0.0f;

    float sum = 0.0f;
    int cnt = 0;
    for (int t = tid; t < tm; t += 256) {
        if (r[t] < C_SIZE) {
            float dd = s[t] - best;
            sum += (dd > 0.0f) ? dd : 0.0f;
            ++cnt;
        }
    }
    red_f[tid] = sum;
    red_c[tid] = cnt;
    __syncthreads();
    for (int off = 128; off; off >>= 1) {
        if (tid < off) { red_f[tid] += red_f[tid + off]; red_c[tid] += red_c[tid + off]; }
        __syncthreads();
    }
    if (tid == 0) loss[item] = red_f[0] / (float)((red_c[0] > 1) ? red_c[0] : 1);
}

// ---------------------------------------------------------------------------
// Kernel D2: mean over 128 per-item losses.
// ---------------------------------------------------------------------------
__global__ void finalize_mean(const float* __restrict__ loss, float* __restrict__ out) {
    __shared__ float red[B_SIZE];
    int i = (int)threadIdx.x;
    red[i] = loss[i];
    __syncthreads();
    for (int off = 64; off; off >>= 1) {
        if (i < off) red[i] += red[i + off];
        __syncthreads();
    }
    if (i == 0) out[0] = red[0] / (float)B_SIZE;
}

extern "C" void kernel_launch(void* const* d_in, const int* in_sizes, int n_in,
                              void* d_out, int out_size, void* d_ws, size_t ws_size,
                              hipStream_t stream) {
    const float* y_hat  = (const float*)d_in[0];  // [128, 900]
    const float* y_true = (const float*)d_in[1];  // [128, 900] 0/1
    // d_in[2] = sol_true (unused)
    const float* cache  = (const float*)d_in[3];  // [32768, 900] 0/1

    char* ws = (char*)d_ws;
    u64*   cbitsT = (u64*)ws;                                  // 15*32768*8 = 3.75 MiB
    u64*   ybits  = (u64*)(ws + (4u << 20));                   // 16 KiB
    u16*   repc   = (u16*)(ws + (4u << 20) + (64u << 10));     // 16*128*901*2 = 3.52 MiB
    int*   rep    = (int*)(ws + (8u << 20));                   // 461 KiB
    float* svals  = (float*)(ws + (8u << 20) + (512u << 10));  // 461 KiB
    float* loss   = (float*)(ws + (9u << 20));                 // 512 B

    int total_waves = C_SIZE + B_SIZE;                 // 32896
    int pack_blocks = (total_waves + 3) / 4;           // 4 waves per 256-thr block
    pack_bits_all<<<dim3(pack_blocks), 256, 0, stream>>>(cache, y_true, cbitsT, ybits);
    compute_rep<<<dim3(CHUNKS, B_SIZE / IPB), 256, 0, stream>>>(cbitsT, ybits, repc);
    gather_s<<<dim3(16, B_SIZE), 256, 0, stream>>>(cbitsT, y_hat, repc, rep, svals);
    finalize_item<<<dim3(B_SIZE), 256, 0, stream>>>(rep, svals, loss);
    finalize_mean<<<1, B_SIZE, 0, stream>>>(loss, (float*)d_out);
}